// Round 3
// baseline (328.261 us; speedup 1.0000x reference)
//
#include <hip/hip_runtime.h>

#define B_ 2
#define S_ 2048
#define E_ 1024
#define H_ 16
#define D_ 64

typedef short  s16x8 __attribute__((ext_vector_type(8)));
typedef float  f32x4 __attribute__((ext_vector_type(4)));
typedef unsigned short u16x4 __attribute__((ext_vector_type(4)));

__device__ __forceinline__ ushort f2bf(float f) {
    union { float f; unsigned u; } x; x.f = f;
    unsigned u = x.u + 0x7fffu + ((x.u >> 16) & 1u);   // RNE
    return (ushort)(u >> 16);
}

// ---------------------------------------------------------------------------
// X fp32 -> bf16 (flat, 4 elems/thread)
// ---------------------------------------------------------------------------
__global__ __launch_bounds__(256) void cvtx_kernel(
    const float* __restrict__ X, ushort* __restrict__ Xbf)
{
    int i = (blockIdx.x * 256 + threadIdx.x) * 4;
    float4 v = *(const float4*)&X[i];
    u16x4 o;
    o.x = f2bf(v.x); o.y = f2bf(v.y); o.z = f2bf(v.z); o.w = f2bf(v.w);
    *(u16x4*)&Xbf[i] = o;
}

// ---------------------------------------------------------------------------
// W fp32 [Kdim][Ndim] -> Wt bf16 [Ndim][Kdim]  (64x64 LDS tiles)
// ---------------------------------------------------------------------------
__global__ __launch_bounds__(256) void wtrans_kernel(
    const float* __restrict__ W, ushort* __restrict__ Wt, int Kdim, int Ndim)
{
    __shared__ float tile[64][65];
    int n0 = blockIdx.x * 64, k0 = blockIdx.y * 64;
    int tid = threadIdx.x;
    int c = tid & 63;
#pragma unroll
    for (int r = tid >> 6; r < 64; r += 4)
        tile[r][c] = W[(size_t)(k0 + r) * Ndim + n0 + c];
    __syncthreads();
#pragma unroll
    for (int r = tid >> 6; r < 64; r += 4)
        Wt[(size_t)(n0 + r) * Kdim + k0 + c] = f2bf(tile[c][r]);
}

// ---------------------------------------------------------------------------
// bf16 MFMA GEMM (m97 structure): C[m][n] = sum_k A[m][k]*Bt[n][k] + bias[n]
// 128x128 tile, BK=32, global_load_lds w=16, ds_read_b128 frags.
// mode 0: fp32 C0. mode 1 (N=3E): seg0->Qbf, seg1->Kf32+Kbf, seg2->Vf32.
// ---------------------------------------------------------------------------
__global__ __launch_bounds__(256) void gemm_mfma_bt(
    const ushort* __restrict__ A,    // [M][K] bf16
    const ushort* __restrict__ Bt,   // [N][K] bf16
    const float* __restrict__ bias,  // [N]
    int M, int N, int K,
    float* __restrict__ C0,
    ushort* __restrict__ Qbf, float* __restrict__ Kf32, ushort* __restrict__ Kbf,
    float* __restrict__ Vf32, int mode)
{
    __shared__ ushort As[128 * 32];
    __shared__ ushort Bs[128 * 32];
    int tid = threadIdx.x;
    int wid = tid >> 6, lane = tid & 63;
    int l15 = lane & 15, quad = lane >> 4;
    int wm = wid >> 1, wn = wid & 1;
    int row0 = blockIdx.y * 128, col0 = blockIdx.x * 128;

    int sr = wid * 16 + (lane >> 2);
    int sk = (lane & 3) * 8;

    f32x4 acc[4][4];
#pragma unroll
    for (int mt = 0; mt < 4; mt++)
#pragma unroll
        for (int nt = 0; nt < 4; nt++) acc[mt][nt] = (f32x4){0.f, 0.f, 0.f, 0.f};

    for (int k0 = 0; k0 < K; k0 += 32) {
        __syncthreads();
#pragma unroll
        for (int c = 0; c < 2; c++) {
            int r = c * 64 + sr;
            __builtin_amdgcn_global_load_lds(
                (const __attribute__((address_space(1))) unsigned int*)
                    &A[(size_t)(row0 + r) * K + k0 + sk],
                (__attribute__((address_space(3))) unsigned int*)&As[r * 32 + sk],
                16, 0, 0);
            __builtin_amdgcn_global_load_lds(
                (const __attribute__((address_space(1))) unsigned int*)
                    &Bt[(size_t)(col0 + r) * K + k0 + sk],
                (__attribute__((address_space(3))) unsigned int*)&Bs[r * 32 + sk],
                16, 0, 0);
        }
        __syncthreads();

        s16x8 af[4], bf[4];
#pragma unroll
        for (int mt = 0; mt < 4; mt++)
            af[mt] = *(const s16x8*)&As[(wm * 64 + mt * 16 + l15) * 32 + quad * 8];
#pragma unroll
        for (int nt = 0; nt < 4; nt++)
            bf[nt] = *(const s16x8*)&Bs[(wn * 64 + nt * 16 + l15) * 32 + quad * 8];
#pragma unroll
        for (int mt = 0; mt < 4; mt++)
#pragma unroll
            for (int nt = 0; nt < 4; nt++)
                acc[mt][nt] = __builtin_amdgcn_mfma_f32_16x16x32_bf16(
                    af[mt], bf[nt], acc[mt][nt], 0, 0, 0);
    }

#pragma unroll
    for (int nt = 0; nt < 4; nt++) {
        int n = col0 + wn * 64 + nt * 16 + l15;
        float bv = bias[n];
        if (mode == 1) {
            int seg = n >> 10;
            int nn = n & (E_ - 1);
#pragma unroll
            for (int mt = 0; mt < 4; mt++)
#pragma unroll
                for (int r = 0; r < 4; r++) {
                    int row = row0 + wm * 64 + mt * 16 + quad * 4 + r;
                    float v = acc[mt][nt][r] + bv;
                    size_t idx = (size_t)row * E_ + nn;
                    if (seg == 0)      Qbf[idx] = f2bf(v);
                    else if (seg == 1) { Kf32[idx] = v; Kbf[idx] = f2bf(v); }
                    else               Vf32[idx] = v;
                }
        } else {
#pragma unroll
            for (int mt = 0; mt < 4; mt++)
#pragma unroll
                for (int r = 0; r < 4; r++) {
                    int row = row0 + wm * 64 + mt * 16 + quad * 4 + r;
                    C0[(size_t)row * N + n] = acc[mt][nt][r] + bv;
                }
        }
    }
}

// ---------------------------------------------------------------------------
// V transpose: fp32 V [b*S+s][h*64+d] -> bf16 Vt [(b*H+h)*64+d][s]
// ---------------------------------------------------------------------------
__global__ __launch_bounds__(256) void vtrans_kernel(
    const float* __restrict__ V, ushort* __restrict__ Vt)
{
    __shared__ float tile[64][65];
    int blk = blockIdx.x;
    int s0 = (blk & 31) * 64;
    int bh = blk >> 5;
    int b = bh >> 4, h = bh & 15;
    int tid = threadIdx.x;
    int d = tid & 63;
#pragma unroll
    for (int i = tid >> 6; i < 64; i += 4)
        tile[i][d] = V[((size_t)(b * S_ + s0 + i)) * E_ + h * 64 + d];
    __syncthreads();
    int lane = tid & 63, w = tid >> 6;
#pragma unroll
    for (int dd = w; dd < 64; dd += 4)
        Vt[((size_t)(bh * 64 + dd)) * S_ + s0 + lane] = f2bf(tile[lane][dd]);
}

// ---------------------------------------------------------------------------
// MFMA flash attention, fixed-reference softmax — BARRIER-FREE (round 8).
// Diagnosis from rounds 0-2: occupancy-insensitive, all pipes <40% busy ->
// the 4-wave barrier lockstep (barrier, LDS-stage, barrier per tile) was the
// stall, not residency. K/V per (b,h) is 256KB each and L2-resident, so the
// LDS staging that forced the barriers is unnecessary sharing: each wave now
// reads K/V MFMA fragments DIRECTLY from L2 (64B-contiguous per row), and
// both __syncthreads() are deleted. Waves run fully independently.
// XCD-aware mapping: blk%8 = XCD slot; each XCD sees only 4 distinct (b,h)
// streams -> K+Vt working set 2MB < 4MB L2 per XCD. qt balance per XCD is
// exact (4 blocks of every qt), and LPT order (qt descending) is preserved.
// Ps (P bf16 staging for the PV A-fragment) stays: wave-private, no barrier,
// XOR-swizzled as before.
// ---------------------------------------------------------------------------
__global__ __launch_bounds__(256) void attn_mfma_kernel(
    const ushort* __restrict__ Qbf,  // [B*S, E] bf16
    const ushort* __restrict__ Kbf,  // [B*S, E] bf16
    const ushort* __restrict__ Vt,   // [(b*H+h)*64+d][S] bf16
    const float* __restrict__ bias,  // [S,S]
    ushort* __restrict__ Ctx)        // [B*S, E] bf16
{
    __shared__ ushort Ps[4][16][72];

    int blk = blockIdx.x;
    int x  = blk & 7;                // XCD slot
    int g  = blk >> 3;               // 0..127
    int bh = x + 8 * (g & 3);        // 4 distinct bh per XCD
    int qt = 31 - (g >> 2);          // LPT within each XCD
    int b = bh >> 4, h = bh & 15;
    int tid = threadIdx.x;
    int wid = tid >> 6, lane = tid & 63;
    int l15 = lane & 15, quad = lane >> 4;
    const float scale = 0.125f;

    int q0w = qt * 64 + wid * 16;

    // Q fragments (A-layout)
    const size_t qbase = ((size_t)(b * S_ + q0w + l15)) * E_ + h * 64 + quad * 8;
    s16x8 qa0 = *(const s16x8*)&Qbf[qbase];
    s16x8 qa1 = *(const s16x8*)&Qbf[qbase + 32];

    // direct-fragment base pointers (replace LDS staging)
    // K frag kt: row b*S + j0 + kt*16 + l15, cols h*64 + quad*8 (+32)
    const ushort* kbase = &Kbf[(size_t)(b * S_ + l15) * E_ + h * 64 + quad * 8];
    // V frag dt: row bh*64 + dt*16 + l15, cols j0 + quad*8 (+32)
    const ushort* vbase = &Vt[(size_t)(bh * 64 + l15) * S_ + quad * 8];
    // bias: row q0w + quad*4 + r, col j0 + kt*16 + l15
    const float*  bbase = &bias[(size_t)(q0w + quad * 4) * S_ + l15];

    f32x4 o[4];
#pragma unroll
    for (int dt = 0; dt < 4; dt++) o[dt] = (f32x4){0.f, 0.f, 0.f, 0.f};
    float lsum[4];
#pragma unroll
    for (int r = 0; r < 4; r++) lsum[r] = 0.f;

    for (int t = 0; t <= qt; t++) {
        int j0 = t * 64;

        // ---- issue bias loads first (needed after QKT; latency hidden)
        float bv[4][4];
#pragma unroll
        for (int r = 0; r < 4; r++)
#pragma unroll
            for (int kt = 0; kt < 4; kt++)
                bv[r][kt] = bbase[(size_t)r * S_ + j0 + kt * 16];

        // ---- K fragments direct from L2
        s16x8 kb0[4], kb1[4];
#pragma unroll
        for (int kt = 0; kt < 4; kt++) {
            const ushort* kp = &kbase[(size_t)(j0 + kt * 16) * E_];
            kb0[kt] = *(const s16x8*)kp;
            kb1[kt] = *(const s16x8*)(kp + 32);
        }

        // ---- V fragments direct from L2 (used after softmax; issue early)
        s16x8 vb0[4], vb1[4];
#pragma unroll
        for (int dt = 0; dt < 4; dt++) {
            const ushort* vp = &vbase[(size_t)(dt * 16) * S_ + j0];
            vb0[dt] = *(const s16x8*)vp;
            vb1[dt] = *(const s16x8*)(vp + 32);
        }

        // ---- S = Q K^T : rows=q(quad*4+r), cols=key(kt*16+l15)
        f32x4 s[4];
#pragma unroll
        for (int kt = 0; kt < 4; kt++) {
            f32x4 acc = (f32x4){0.f, 0.f, 0.f, 0.f};
            acc = __builtin_amdgcn_mfma_f32_16x16x32_bf16(qa0, kb0[kt], acc, 0, 0, 0);
            acc = __builtin_amdgcn_mfma_f32_16x16x32_bf16(qa1, kb1[kt], acc, 0, 0, 0);
            s[kt] = acc;
        }

        // ---- p = exp(s*scale + bias); causal mask -> 0; XOR-swizzled P
        bool diag = (t == qt);
#pragma unroll
        for (int r = 0; r < 4; r++) {
            int row = q0w + quad * 4 + r;
#pragma unroll
            for (int kt = 0; kt < 4; kt++) {
                int j = j0 + kt * 16 + l15;
                float v = s[kt][r] * scale + bv[r][kt];
                float p = (diag && j > row) ? 0.f : __expf(v);
                lsum[r] += p;
                int chunk = (kt * 2 + (l15 >> 3)) ^ quad;
                Ps[wid][quad * 4 + r][chunk * 8 + (l15 & 7)] = f2bf(p);
            }
        }

        // ---- O += P V  (Ps wave-private: no barrier)
        int cb = (quad ^ (l15 >> 2)) * 8;
        s16x8 pa0 = *(const s16x8*)&Ps[wid][l15][cb];
        s16x8 pa1 = *(const s16x8*)&Ps[wid][l15][cb + 32];
#pragma unroll
        for (int dt = 0; dt < 4; dt++) {
            o[dt] = __builtin_amdgcn_mfma_f32_16x16x32_bf16(pa0, vb0[dt], o[dt], 0, 0, 0);
            o[dt] = __builtin_amdgcn_mfma_f32_16x16x32_bf16(pa1, vb1[dt], o[dt], 0, 0, 0);
        }
    }

    // ---- single final row-sum reduction
    float inv_l[4];
#pragma unroll
    for (int r = 0; r < 4; r++) {
        float l = lsum[r];
        l += __shfl_xor(l, 1);
        l += __shfl_xor(l, 2);
        l += __shfl_xor(l, 4);
        l += __shfl_xor(l, 8);
        inv_l[r] = 1.f / l;
    }

#pragma unroll
    for (int dt = 0; dt < 4; dt++) {
#pragma unroll
        for (int r = 0; r < 4; r++) {
            int row = q0w + quad * 4 + r;
            Ctx[((size_t)(b * S_ + row)) * E_ + h * 64 + dt * 16 + l15] =
                f2bf(o[dt][r] * inv_l[r]);
        }
    }
}

// ---------------------------------------------------------------------------
extern "C" void kernel_launch(void* const* d_in, const int* in_sizes, int n_in,
                              void* d_out, int out_size, void* d_ws, size_t ws_size,
                              hipStream_t stream) {
    const float* X     = (const float*)d_in[0];
    const float* abias = (const float*)d_in[1];
    const float* Wqkv  = (const float*)d_in[2];
    const float* bqkv  = (const float*)d_in[3];
    const float* Wproj = (const float*)d_in[4];
    const float* bproj = (const float*)d_in[5];

    const size_t plane = (size_t)B_ * S_ * E_;   // 4,194,304
    float* out  = (float*)d_out;
    float* kout = out + plane;                   // cache_key (fp32 output)
    float* vout = kout + plane;                  // cache_value (fp32 output)

    // workspace: 4 bf16 planes + weights = 42 MB (proven footprint).
    // ctxbf ALIASES xbf (X's bf16 copy is dead after the QKV GEMM).
    ushort* xbf    = (ushort*)d_ws;
    ushort* qbf    = xbf + plane;
    ushort* kbf    = qbf + plane;
    ushort* vt     = kbf + plane;
    ushort* ctxbf  = xbf;                        // alias (see above)
    ushort* wqkvt  = vt + plane;                 // [3E][E]
    ushort* wprojt = wqkvt + (size_t)3 * E_ * E_;// [E][E]

    const int M = B_ * S_;

    cvtx_kernel<<<dim3(plane / 1024), 256, 0, stream>>>(X, xbf);
    wtrans_kernel<<<dim3(3 * E_ / 64, E_ / 64), 256, 0, stream>>>(Wqkv, wqkvt, E_, 3 * E_);
    wtrans_kernel<<<dim3(E_ / 64, E_ / 64), 256, 0, stream>>>(Wproj, wprojt, E_, E_);

    gemm_mfma_bt<<<dim3(3 * E_ / 128, M / 128), 256, 0, stream>>>(
        xbf, wqkvt, bqkv, M, 3 * E_, E_,
        nullptr, qbf, kout, kbf, vout, 1);

    vtrans_kernel<<<dim3(B_ * H_ * (S_ / 64)), 256, 0, stream>>>(vout, vt);

    // flash attention: 1024 barrier-free blocks, XCD-clustered bh, LPT qt
    attn_mfma_kernel<<<dim3(B_ * H_ * 32), 256, 0, stream>>>(
        qbf, kbf, vt, abias, ctxbf);

    gemm_mfma_bt<<<dim3(E_ / 128, M / 128), 256, 0, stream>>>(
        ctxbf, wprojt, bproj, M, E_, E_,
        out, nullptr, nullptr, nullptr, nullptr, 0);
}

// Round 4
// 265.874 us; speedup vs baseline: 1.2347x; 1.2347x over previous
//
#include <hip/hip_runtime.h>

#define B_ 2
#define S_ 2048
#define E_ 1024
#define H_ 16
#define D_ 64

typedef short  s16x8 __attribute__((ext_vector_type(8)));
typedef float  f32x4 __attribute__((ext_vector_type(4)));
typedef unsigned short u16x4 __attribute__((ext_vector_type(4)));

__device__ __forceinline__ ushort f2bf(float f) {
    union { float f; unsigned u; } x; x.f = f;
    unsigned u = x.u + 0x7fffu + ((x.u >> 16) & 1u);   // RNE
    return (ushort)(u >> 16);
}

// ---------------------------------------------------------------------------
// X fp32 -> bf16 (flat, 4 elems/thread)
// ---------------------------------------------------------------------------
__global__ __launch_bounds__(256) void cvtx_kernel(
    const float* __restrict__ X, ushort* __restrict__ Xbf)
{
    int i = (blockIdx.x * 256 + threadIdx.x) * 4;
    float4 v = *(const float4*)&X[i];
    u16x4 o;
    o.x = f2bf(v.x); o.y = f2bf(v.y); o.z = f2bf(v.z); o.w = f2bf(v.w);
    *(u16x4*)&Xbf[i] = o;
}

// ---------------------------------------------------------------------------
// W fp32 [Kdim][Ndim] -> Wt bf16 [Ndim][Kdim]  (64x64 LDS tiles)
// ---------------------------------------------------------------------------
__global__ __launch_bounds__(256) void wtrans_kernel(
    const float* __restrict__ W, ushort* __restrict__ Wt, int Kdim, int Ndim)
{
    __shared__ float tile[64][65];
    int n0 = blockIdx.x * 64, k0 = blockIdx.y * 64;
    int tid = threadIdx.x;
    int c = tid & 63;
#pragma unroll
    for (int r = tid >> 6; r < 64; r += 4)
        tile[r][c] = W[(size_t)(k0 + r) * Ndim + n0 + c];
    __syncthreads();
#pragma unroll
    for (int r = tid >> 6; r < 64; r += 4)
        Wt[(size_t)(n0 + r) * Kdim + k0 + c] = f2bf(tile[c][r]);
}

// ---------------------------------------------------------------------------
// bf16 MFMA GEMM (m97 structure): C[m][n] = sum_k A[m][k]*Bt[n][k] + bias[n]
// 128x128 tile, BK=32, global_load_lds w=16, ds_read_b128 frags.
// mode 0: fp32 C0. mode 1 (N=3E): seg0->Qbf, seg1->Kf32+Kbf, seg2->Vf32.
// ---------------------------------------------------------------------------
__global__ __launch_bounds__(256) void gemm_mfma_bt(
    const ushort* __restrict__ A,    // [M][K] bf16
    const ushort* __restrict__ Bt,   // [N][K] bf16
    const float* __restrict__ bias,  // [N]
    int M, int N, int K,
    float* __restrict__ C0,
    ushort* __restrict__ Qbf, float* __restrict__ Kf32, ushort* __restrict__ Kbf,
    float* __restrict__ Vf32, int mode)
{
    __shared__ ushort As[128 * 32];
    __shared__ ushort Bs[128 * 32];
    int tid = threadIdx.x;
    int wid = tid >> 6, lane = tid & 63;
    int l15 = lane & 15, quad = lane >> 4;
    int wm = wid >> 1, wn = wid & 1;
    int row0 = blockIdx.y * 128, col0 = blockIdx.x * 128;

    int sr = wid * 16 + (lane >> 2);
    int sk = (lane & 3) * 8;

    f32x4 acc[4][4];
#pragma unroll
    for (int mt = 0; mt < 4; mt++)
#pragma unroll
        for (int nt = 0; nt < 4; nt++) acc[mt][nt] = (f32x4){0.f, 0.f, 0.f, 0.f};

    for (int k0 = 0; k0 < K; k0 += 32) {
        __syncthreads();
#pragma unroll
        for (int c = 0; c < 2; c++) {
            int r = c * 64 + sr;
            __builtin_amdgcn_global_load_lds(
                (const __attribute__((address_space(1))) unsigned int*)
                    &A[(size_t)(row0 + r) * K + k0 + sk],
                (__attribute__((address_space(3))) unsigned int*)&As[r * 32 + sk],
                16, 0, 0);
            __builtin_amdgcn_global_load_lds(
                (const __attribute__((address_space(1))) unsigned int*)
                    &Bt[(size_t)(col0 + r) * K + k0 + sk],
                (__attribute__((address_space(3))) unsigned int*)&Bs[r * 32 + sk],
                16, 0, 0);
        }
        __syncthreads();

        s16x8 af[4], bf[4];
#pragma unroll
        for (int mt = 0; mt < 4; mt++)
            af[mt] = *(const s16x8*)&As[(wm * 64 + mt * 16 + l15) * 32 + quad * 8];
#pragma unroll
        for (int nt = 0; nt < 4; nt++)
            bf[nt] = *(const s16x8*)&Bs[(wn * 64 + nt * 16 + l15) * 32 + quad * 8];
#pragma unroll
        for (int mt = 0; mt < 4; mt++)
#pragma unroll
            for (int nt = 0; nt < 4; nt++)
                acc[mt][nt] = __builtin_amdgcn_mfma_f32_16x16x32_bf16(
                    af[mt], bf[nt], acc[mt][nt], 0, 0, 0);
    }

#pragma unroll
    for (int nt = 0; nt < 4; nt++) {
        int n = col0 + wn * 64 + nt * 16 + l15;
        float bv = bias[n];
        if (mode == 1) {
            int seg = n >> 10;
            int nn = n & (E_ - 1);
#pragma unroll
            for (int mt = 0; mt < 4; mt++)
#pragma unroll
                for (int r = 0; r < 4; r++) {
                    int row = row0 + wm * 64 + mt * 16 + quad * 4 + r;
                    float v = acc[mt][nt][r] + bv;
                    size_t idx = (size_t)row * E_ + nn;
                    if (seg == 0)      Qbf[idx] = f2bf(v);
                    else if (seg == 1) { Kf32[idx] = v; Kbf[idx] = f2bf(v); }
                    else               Vf32[idx] = v;
                }
        } else {
#pragma unroll
            for (int mt = 0; mt < 4; mt++)
#pragma unroll
                for (int r = 0; r < 4; r++) {
                    int row = row0 + wm * 64 + mt * 16 + quad * 4 + r;
                    C0[(size_t)row * N + n] = acc[mt][nt][r] + bv;
                }
        }
    }
}

// ---------------------------------------------------------------------------
// V transpose: fp32 V [b*S+s][h*64+d] -> bf16 Vt [(b*H+h)*64+d][s]
// ---------------------------------------------------------------------------
__global__ __launch_bounds__(256) void vtrans_kernel(
    const float* __restrict__ V, ushort* __restrict__ Vt)
{
    __shared__ float tile[64][65];
    int blk = blockIdx.x;
    int s0 = (blk & 31) * 64;
    int bh = blk >> 5;
    int b = bh >> 4, h = bh & 15;
    int tid = threadIdx.x;
    int d = tid & 63;
#pragma unroll
    for (int i = tid >> 6; i < 64; i += 4)
        tile[i][d] = V[((size_t)(b * S_ + s0 + i)) * E_ + h * 64 + d];
    __syncthreads();
    int lane = tid & 63, w = tid >> 6;
#pragma unroll
    for (int dd = w; dd < 64; dd += 4)
        Vt[((size_t)(bh * 64 + dd)) * S_ + s0 + lane] = f2bf(tile[lane][dd]);
}

// ---------------------------------------------------------------------------
// MFMA flash attention, fixed-reference softmax — round 9.
// Evidence so far: R2 (staged, 2 barriers/tile) 62us with LDS pipe ~77% busy
// (1440cy LDS + 288 conflict vs 2254cy wall per tile-unit); R3 (no LDS, no
// prefetch) 152us = pure L2-latency serialization. This version keeps the
// proven cross-tile prefetch and removes measured LDS cost:
//  - V is NEVER staged in LDS: B-fragments read directly from L2 (addressing
//    validated in R3), issued at tile top so QKT+softmax (~400cy) hides their
//    ~250cy L2 latency inside the tile. Removes 8 ds_read + 2 ds_write /wave/tile.
//  - K LDS is DOUBLE-BUFFERED with a single barrier per tile: Ks[nxt] is
//    written from prefetch regs during tile t's compute; barrier at iteration
//    end covers both RAW (next tile reads) and WAR (buffer reuse) hazards.
//  - K global prefetch runs two tiles ahead (kr regs), bias one tile ahead
//    (bvn reused in-place after softmax consumes it; saves 16 VGPR).
// Ps (wave-private P staging, XOR-swizzled) unchanged.
// LDS ops/wave/tile: 38 -> 28; barriers/tile: 2 -> 1.
// ---------------------------------------------------------------------------
__global__ __launch_bounds__(256) void attn_mfma_kernel(
    const ushort* __restrict__ Qbf,  // [B*S, E] bf16
    const ushort* __restrict__ Kbf,  // [B*S, E] bf16
    const ushort* __restrict__ Vt,   // [(b*H+h)*64+d][S] bf16
    const float* __restrict__ bias,  // [S,S]
    ushort* __restrict__ Ctx)        // [B*S, E] bf16
{
    __shared__ ushort Ks[2][64][72];
    __shared__ ushort Ps[4][16][72];

    int blk = blockIdx.x;
    int bh = blk & 31;
    int qt = 31 - (blk >> 5);        // largest q-tiles dispatched first (LPT)
    int b = bh >> 4, h = bh & 15;
    int tid = threadIdx.x;
    int wid = tid >> 6, lane = tid & 63;
    int l15 = lane & 15, quad = lane >> 4;

    int skey = tid >> 2;
    int scol = (tid & 3) * 16;
    const float scale = 0.125f;

    const size_t krow = (size_t)(b * S_ + skey) * E_ + h * 64 + scol; // + j0*E_

    int q0w = qt * 64 + wid * 16;

    // Q fragments (A-layout)
    const size_t qbase = ((size_t)(b * S_ + q0w + l15)) * E_ + h * 64 + quad * 8;
    s16x8 qa0 = *(const s16x8*)&Qbf[qbase];
    s16x8 qa1 = *(const s16x8*)&Qbf[qbase + 32];

    // V direct-fragment base (validated in R3):
    // frag dt: row bh*64 + dt*16 + l15, cols j0 + quad*8 (+32)
    const ushort* vbase = &Vt[(size_t)(bh * 64 + l15) * S_ + quad * 8];
    // bias: row q0w + quad*4 + r, col j0 + kt*16 + l15
    const float*  bbase = &bias[(size_t)(q0w + quad * 4) * S_ + l15];

    f32x4 o[4];
#pragma unroll
    for (int dt = 0; dt < 4; dt++) o[dt] = (f32x4){0.f, 0.f, 0.f, 0.f};
    float lsum[4];
#pragma unroll
    for (int r = 0; r < 4; r++) lsum[r] = 0.f;

    // ---- prologue: stage K tile 0, prefetch K tile 1, load bias tile 0
    float4 kr0 = ((const float4*)&Kbf[krow])[0];
    float4 kr1 = ((const float4*)&Kbf[krow])[1];
    *(float4*)&Ks[0][skey][scol]     = kr0;
    *(float4*)&Ks[0][skey][scol + 8] = kr1;
    if (qt >= 1) {
        kr0 = ((const float4*)&Kbf[krow + (size_t)64 * E_])[0];
        kr1 = ((const float4*)&Kbf[krow + (size_t)64 * E_])[1];
    }
    float bvn[4][4];
#pragma unroll
    for (int r = 0; r < 4; r++)
#pragma unroll
        for (int kt = 0; kt < 4; kt++)
            bvn[r][kt] = bbase[(size_t)r * S_ + kt * 16];
    __syncthreads();

    for (int t = 0; t <= qt; t++) {
        int j0 = t * 64;
        int cur = t & 1, nxt = cur ^ 1;

        // ---- V fragments for THIS tile, direct from L2 (consumed by PV,
        //      ~400cy after issue: latency hidden under QKT + softmax)
        s16x8 vb0[4], vb1[4];
#pragma unroll
        for (int dt = 0; dt < 4; dt++) {
            const ushort* vp = &vbase[(size_t)(dt * 16) * S_ + j0];
            vb0[dt] = *(const s16x8*)vp;
            vb1[dt] = *(const s16x8*)(vp + 32);
        }

        // ---- S = Q K^T from Ks[cur]
        f32x4 s[4];
#pragma unroll
        for (int kt = 0; kt < 4; kt++) {
            s16x8 kb0 = *(const s16x8*)&Ks[cur][kt * 16 + l15][quad * 8];
            s16x8 kb1 = *(const s16x8*)&Ks[cur][kt * 16 + l15][quad * 8 + 32];
            f32x4 acc = (f32x4){0.f, 0.f, 0.f, 0.f};
            acc = __builtin_amdgcn_mfma_f32_16x16x32_bf16(qa0, kb0, acc, 0, 0, 0);
            acc = __builtin_amdgcn_mfma_f32_16x16x32_bf16(qa1, kb1, acc, 0, 0, 0);
            s[kt] = acc;
        }

        // ---- stage K(t+1) into the other buffer (overlaps with compute;
        //      made visible by the end-of-iteration barrier)
        if (t < qt) {
            *(float4*)&Ks[nxt][skey][scol]     = kr0;
            *(float4*)&Ks[nxt][skey][scol + 8] = kr1;
        }
        // ---- prefetch K(t+2) into registers
        if (t + 2 <= qt) {
            size_t koff = krow + (size_t)((t + 2) * 64) * E_;
            kr0 = ((const float4*)&Kbf[koff])[0];
            kr1 = ((const float4*)&Kbf[koff])[1];
        }

        // ---- p = exp(s*scale + bias); causal mask -> 0; XOR-swizzled P
        bool diag = (t == qt);
#pragma unroll
        for (int r = 0; r < 4; r++) {
            int row = q0w + quad * 4 + r;
#pragma unroll
            for (int kt = 0; kt < 4; kt++) {
                int j = j0 + kt * 16 + l15;
                float v = s[kt][r] * scale + bvn[r][kt];
                float p = (diag && j > row) ? 0.f : __expf(v);
                lsum[r] += p;
                int chunk = (kt * 2 + (l15 >> 3)) ^ quad;
                Ps[wid][quad * 4 + r][chunk * 8 + (l15 & 7)] = f2bf(p);
            }
        }

        // ---- prefetch bias(t+1) into bvn (softmax above already consumed it)
        if (t < qt) {
#pragma unroll
            for (int r = 0; r < 4; r++)
#pragma unroll
                for (int kt = 0; kt < 4; kt++)
                    bvn[r][kt] = bbase[(size_t)r * S_ + j0 + 64 + kt * 16];
        }

        // ---- O += P V  (Ps wave-private: no barrier; V frags from regs)
        int cb = (quad ^ (l15 >> 2)) * 8;
        s16x8 pa0 = *(const s16x8*)&Ps[wid][l15][cb];
        s16x8 pa1 = *(const s16x8*)&Ps[wid][l15][cb + 32];
#pragma unroll
        for (int dt = 0; dt < 4; dt++) {
            o[dt] = __builtin_amdgcn_mfma_f32_16x16x32_bf16(pa0, vb0[dt], o[dt], 0, 0, 0);
            o[dt] = __builtin_amdgcn_mfma_f32_16x16x32_bf16(pa1, vb1[dt], o[dt], 0, 0, 0);
        }

        __syncthreads();   // single barrier: Ks[nxt] visible, Ks[cur] release
    }

    // ---- single final row-sum reduction
    float inv_l[4];
#pragma unroll
    for (int r = 0; r < 4; r++) {
        float l = lsum[r];
        l += __shfl_xor(l, 1);
        l += __shfl_xor(l, 2);
        l += __shfl_xor(l, 4);
        l += __shfl_xor(l, 8);
        inv_l[r] = 1.f / l;
    }

#pragma unroll
    for (int dt = 0; dt < 4; dt++) {
#pragma unroll
        for (int r = 0; r < 4; r++) {
            int row = q0w + quad * 4 + r;
            Ctx[((size_t)(b * S_ + row)) * E_ + h * 64 + dt * 16 + l15] =
                f2bf(o[dt][r] * inv_l[r]);
        }
    }
}

// ---------------------------------------------------------------------------
extern "C" void kernel_launch(void* const* d_in, const int* in_sizes, int n_in,
                              void* d_out, int out_size, void* d_ws, size_t ws_size,
                              hipStream_t stream) {
    const float* X     = (const float*)d_in[0];
    const float* abias = (const float*)d_in[1];
    const float* Wqkv  = (const float*)d_in[2];
    const float* bqkv  = (const float*)d_in[3];
    const float* Wproj = (const float*)d_in[4];
    const float* bproj = (const float*)d_in[5];

    const size_t plane = (size_t)B_ * S_ * E_;   // 4,194,304
    float* out  = (float*)d_out;
    float* kout = out + plane;                   // cache_key (fp32 output)
    float* vout = kout + plane;                  // cache_value (fp32 output)

    // workspace: 4 bf16 planes + weights = 42 MB (proven footprint).
    // ctxbf ALIASES xbf (X's bf16 copy is dead after the QKV GEMM).
    ushort* xbf    = (ushort*)d_ws;
    ushort* qbf    = xbf + plane;
    ushort* kbf    = qbf + plane;
    ushort* vt     = kbf + plane;
    ushort* ctxbf  = xbf;                        // alias (see above)
    ushort* wqkvt  = vt + plane;                 // [3E][E]
    ushort* wprojt = wqkvt + (size_t)3 * E_ * E_;// [E][E]

    const int M = B_ * S_;

    cvtx_kernel<<<dim3(plane / 1024), 256, 0, stream>>>(X, xbf);
    wtrans_kernel<<<dim3(3 * E_ / 64, E_ / 64), 256, 0, stream>>>(Wqkv, wqkvt, E_, 3 * E_);
    wtrans_kernel<<<dim3(E_ / 64, E_ / 64), 256, 0, stream>>>(Wproj, wprojt, E_, E_);

    gemm_mfma_bt<<<dim3(3 * E_ / 128, M / 128), 256, 0, stream>>>(
        xbf, wqkvt, bqkv, M, 3 * E_, E_,
        nullptr, qbf, kout, kbf, vout, 1);

    vtrans_kernel<<<dim3(B_ * H_ * (S_ / 64)), 256, 0, stream>>>(vout, vt);

    // flash attention: 1024 blocks, one q-tile each, largest-first (LPT)
    attn_mfma_kernel<<<dim3(B_ * H_ * 32), 256, 0, stream>>>(
        qbf, kbf, vt, abias, ctxbf);

    gemm_mfma_bt<<<dim3(E_ / 128, M / 128), 256, 0, stream>>>(
        ctxbf, wprojt, bproj, M, E_, E_,
        out, nullptr, nullptr, nullptr, nullptr, 0);
}

// Round 5
// 237.203 us; speedup vs baseline: 1.3839x; 1.1209x over previous
//
#include <hip/hip_runtime.h>

#define B_ 2
#define S_ 2048
#define E_ 1024
#define H_ 16
#define D_ 64

typedef short  s16x8 __attribute__((ext_vector_type(8)));
typedef float  f32x4 __attribute__((ext_vector_type(4)));
typedef unsigned short u16x4 __attribute__((ext_vector_type(4)));

__device__ __forceinline__ ushort f2bf(float f) {
    union { float f; unsigned u; } x; x.f = f;
    unsigned u = x.u + 0x7fffu + ((x.u >> 16) & 1u);   // RNE
    return (ushort)(u >> 16);
}

__device__ __forceinline__ float fast_exp2(float x) {
    float r; asm("v_exp_f32 %0, %1" : "=v"(r) : "v"(x)); return r;
}

// ---------------------------------------------------------------------------
// X fp32 -> bf16 (flat, 4 elems/thread)
// ---------------------------------------------------------------------------
__global__ __launch_bounds__(256) void cvtx_kernel(
    const float* __restrict__ X, ushort* __restrict__ Xbf)
{
    int i = (blockIdx.x * 256 + threadIdx.x) * 4;
    float4 v = *(const float4*)&X[i];
    u16x4 o;
    o.x = f2bf(v.x); o.y = f2bf(v.y); o.z = f2bf(v.z); o.w = f2bf(v.w);
    *(u16x4*)&Xbf[i] = o;
}

// ---------------------------------------------------------------------------
// W fp32 [Kdim][Ndim] -> Wt bf16 [Ndim][Kdim]  (64x64 LDS tiles)
// ---------------------------------------------------------------------------
__global__ __launch_bounds__(256) void wtrans_kernel(
    const float* __restrict__ W, ushort* __restrict__ Wt, int Kdim, int Ndim)
{
    __shared__ float tile[64][65];
    int n0 = blockIdx.x * 64, k0 = blockIdx.y * 64;
    int tid = threadIdx.x;
    int c = tid & 63;
#pragma unroll
    for (int r = tid >> 6; r < 64; r += 4)
        tile[r][c] = W[(size_t)(k0 + r) * Ndim + n0 + c];
    __syncthreads();
#pragma unroll
    for (int r = tid >> 6; r < 64; r += 4)
        Wt[(size_t)(n0 + r) * Kdim + k0 + c] = f2bf(tile[c][r]);
}

// ---------------------------------------------------------------------------
// bias fp32 [S][S] -> biasT bf16, causal-packed tile layout, pre-scaled by
// log2(e).  Tile (qi,ki), ki<=qi, L = qi(qi+1)/2 + ki.
// biasT[L*4096 + tid*16 + (r*4+kt)] = bf16(bias[qi*64 + (tid>>6)*16 +
//   ((tid>>4)&3)*4 + r][ki*64 + kt*16 + (tid&15)] * LOG2E)
// This makes each attn thread's 16 bias values for a tile CONTIGUOUS (32B):
// 16 scattered dword loads/lane/tile -> 2 x 16B loads, bytes halved.
// ---------------------------------------------------------------------------
__global__ __launch_bounds__(256) void prep_bias_kernel(
    const float* __restrict__ bias, ushort* __restrict__ biasT)
{
    int L = blockIdx.x;
    int qi = (int)((sqrtf(8.0f * (float)L + 1.0f) - 1.0f) * 0.5f);
    while ((qi + 1) * (qi + 2) / 2 <= L) qi++;
    while (qi * (qi + 1) / 2 > L) qi--;
    int ki = L - qi * (qi + 1) / 2;
    int tid = threadIdx.x;
    int w = tid >> 6, quad = (tid >> 4) & 3, l15 = tid & 15;
    const float LOG2E = 1.4426950408889634f;
    s16x8 h0 = (s16x8){0,0,0,0,0,0,0,0}, h1 = (s16x8){0,0,0,0,0,0,0,0};
#pragma unroll
    for (int r = 0; r < 4; r++)
#pragma unroll
        for (int kt = 0; kt < 4; kt++) {
            float v = bias[(size_t)(qi * 64 + w * 16 + quad * 4 + r) * S_
                           + ki * 64 + kt * 16 + l15] * LOG2E;
            ushort u = f2bf(v);
            int idx = r * 4 + kt;
            if (idx < 8) h0[idx] = (short)u; else h1[idx - 8] = (short)u;
        }
    ushort* dst = &biasT[((size_t)L * 256 + tid) * 16];
    *(s16x8*)dst = h0;
    *(s16x8*)(dst + 8) = h1;
}

// ---------------------------------------------------------------------------
// bf16 MFMA GEMM (m97 structure): C[m][n] = sum_k A[m][k]*Bt[n][k] + bias[n]
// 128x128 tile, BK=32, global_load_lds w=16, ds_read_b128 frags.
// mode 0: fp32 C0. mode 1 (N=3E): seg0->Qbf, seg1->Kf32+Kbf, seg2->Vf32.
// ---------------------------------------------------------------------------
__global__ __launch_bounds__(256) void gemm_mfma_bt(
    const ushort* __restrict__ A,    // [M][K] bf16
    const ushort* __restrict__ Bt,   // [N][K] bf16
    const float* __restrict__ bias,  // [N]
    int M, int N, int K,
    float* __restrict__ C0,
    ushort* __restrict__ Qbf, float* __restrict__ Kf32, ushort* __restrict__ Kbf,
    float* __restrict__ Vf32, int mode)
{
    __shared__ ushort As[128 * 32];
    __shared__ ushort Bs[128 * 32];
    int tid = threadIdx.x;
    int wid = tid >> 6, lane = tid & 63;
    int l15 = lane & 15, quad = lane >> 4;
    int wm = wid >> 1, wn = wid & 1;
    int row0 = blockIdx.y * 128, col0 = blockIdx.x * 128;

    int sr = wid * 16 + (lane >> 2);
    int sk = (lane & 3) * 8;

    f32x4 acc[4][4];
#pragma unroll
    for (int mt = 0; mt < 4; mt++)
#pragma unroll
        for (int nt = 0; nt < 4; nt++) acc[mt][nt] = (f32x4){0.f, 0.f, 0.f, 0.f};

    for (int k0 = 0; k0 < K; k0 += 32) {
        __syncthreads();
#pragma unroll
        for (int c = 0; c < 2; c++) {
            int r = c * 64 + sr;
            __builtin_amdgcn_global_load_lds(
                (const __attribute__((address_space(1))) unsigned int*)
                    &A[(size_t)(row0 + r) * K + k0 + sk],
                (__attribute__((address_space(3))) unsigned int*)&As[r * 32 + sk],
                16, 0, 0);
            __builtin_amdgcn_global_load_lds(
                (const __attribute__((address_space(1))) unsigned int*)
                    &Bt[(size_t)(col0 + r) * K + k0 + sk],
                (__attribute__((address_space(3))) unsigned int*)&Bs[r * 32 + sk],
                16, 0, 0);
        }
        __syncthreads();

        s16x8 af[4], bf[4];
#pragma unroll
        for (int mt = 0; mt < 4; mt++)
            af[mt] = *(const s16x8*)&As[(wm * 64 + mt * 16 + l15) * 32 + quad * 8];
#pragma unroll
        for (int nt = 0; nt < 4; nt++)
            bf[nt] = *(const s16x8*)&Bs[(wn * 64 + nt * 16 + l15) * 32 + quad * 8];
#pragma unroll
        for (int mt = 0; mt < 4; mt++)
#pragma unroll
            for (int nt = 0; nt < 4; nt++)
                acc[mt][nt] = __builtin_amdgcn_mfma_f32_16x16x32_bf16(
                    af[mt], bf[nt], acc[mt][nt], 0, 0, 0);
    }

#pragma unroll
    for (int nt = 0; nt < 4; nt++) {
        int n = col0 + wn * 64 + nt * 16 + l15;
        float bv = bias[n];
        if (mode == 1) {
            int seg = n >> 10;
            int nn = n & (E_ - 1);
#pragma unroll
            for (int mt = 0; mt < 4; mt++)
#pragma unroll
                for (int r = 0; r < 4; r++) {
                    int row = row0 + wm * 64 + mt * 16 + quad * 4 + r;
                    float v = acc[mt][nt][r] + bv;
                    size_t idx = (size_t)row * E_ + nn;
                    if (seg == 0)      Qbf[idx] = f2bf(v);
                    else if (seg == 1) { Kf32[idx] = v; Kbf[idx] = f2bf(v); }
                    else               Vf32[idx] = v;
                }
        } else {
#pragma unroll
            for (int mt = 0; mt < 4; mt++)
#pragma unroll
                for (int r = 0; r < 4; r++) {
                    int row = row0 + wm * 64 + mt * 16 + quad * 4 + r;
                    C0[(size_t)row * N + n] = acc[mt][nt][r] + bv;
                }
        }
    }
}

// ---------------------------------------------------------------------------
// V transpose: fp32 V [b*S+s][h*64+d] -> bf16 Vt [(b*H+h)*64+d][s]
// ---------------------------------------------------------------------------
__global__ __launch_bounds__(256) void vtrans_kernel(
    const float* __restrict__ V, ushort* __restrict__ Vt)
{
    __shared__ float tile[64][65];
    int blk = blockIdx.x;
    int s0 = (blk & 31) * 64;
    int bh = blk >> 5;
    int b = bh >> 4, h = bh & 15;
    int tid = threadIdx.x;
    int d = tid & 63;
#pragma unroll
    for (int i = tid >> 6; i < 64; i += 4)
        tile[i][d] = V[((size_t)(b * S_ + s0 + i)) * E_ + h * 64 + d];
    __syncthreads();
    int lane = tid & 63, w = tid >> 6;
#pragma unroll
    for (int dd = w; dd < 64; dd += 4)
        Vt[((size_t)(bh * 64 + dd)) * S_ + s0 + lane] = f2bf(tile[lane][dd]);
}

// ---------------------------------------------------------------------------
// MFMA flash attention, fixed-reference softmax — round 10.
// Structure = round-0 proven best (512 paired blocks, 4 waves, K/V LDS
// staged, 2 barriers/tile, register prefetch of next K/V tile). Cross-round
// traffic accounting showed time tracks L2/L3 fabric bytes, and bias was the
// dominant term (16KB/tile-unit fp32, 16 scalar loads/lane/tile, 32x
// cross-head duplication, zero L2 locality). Changes vs round 0:
//  1. bias read from biasT (prep_bias_kernel): per lane per tile 2 x 16B
//     contiguous bf16 loads (was 16 scattered dwords), bytes halved,
//     pre-scaled by log2e -> softmax is fma + v_exp_f32 (exp2 direct).
//  2. block mapping blk = bh*16 + pr  ->  XCD = blk%8 = pr%8: all 32 heads
//     on an XCD stream the SAME biasT sequence concurrently -> bias L2 hits.
//     Work per XCD: pr and pr+8 for all bh = exactly 33 units/block, balanced.
// Everything else byte-identical to round 0.
// ---------------------------------------------------------------------------
__global__ __launch_bounds__(256) void attn_mfma_kernel(
    const ushort* __restrict__ Qbf,   // [B*S, E] bf16
    const ushort* __restrict__ Kbf,   // [B*S, E] bf16
    const ushort* __restrict__ Vt,    // [(b*H+h)*64+d][S] bf16
    const ushort* __restrict__ biasT, // causal-packed bf16 tiles (prep_bias)
    ushort* __restrict__ Ctx)         // [B*S, E] bf16
{
    __shared__ ushort Ks[64][72];
    __shared__ ushort Vs[64][72];
    __shared__ ushort Ps[4][16][72];

    int blk = blockIdx.x;
    int bh = blk >> 4;               // 0..31
    int pr = blk & 15;               // 0..15 ; XCD slot = pr % 8
    int b = bh >> 4, h = bh & 15;
    int tid = threadIdx.x;
    int wid = tid >> 6, lane = tid & 63;
    int l15 = lane & 15, quad = lane >> 4;

    int skey = tid >> 2;
    int scol = (tid & 3) * 16;
    const float scale_l2e = 0.18033688011112042f;   // 0.125 * log2(e)

    const size_t krow = (size_t)(b * S_ + skey) * E_ + h * 64 + scol; // + j0*E_
    const size_t vrow = (size_t)(bh * 64 + skey) * S_ + scol;        // + j0

    for (int half = 0; half < 2; half++) {
        int qt = half ? pr : (31 - pr);
        int q0w = qt * 64 + wid * 16;

        // Q fragments (A-layout)
        const size_t qbase = ((size_t)(b * S_ + q0w + l15)) * E_ + h * 64 + quad * 8;
        s16x8 qa0 = *(const s16x8*)&Qbf[qbase];
        s16x8 qa1 = *(const s16x8*)&Qbf[qbase + 32];

        f32x4 o[4];
#pragma unroll
        for (int dt = 0; dt < 4; dt++) o[dt] = (f32x4){0.f, 0.f, 0.f, 0.f};
        float lsum[4];
#pragma unroll
        for (int r = 0; r < 4; r++) lsum[r] = 0.f;

        // ---- preload tile 0 into registers
        float4 kr0 = ((const float4*)&Kbf[krow])[0];
        float4 kr1 = ((const float4*)&Kbf[krow])[1];
        float4 vr0 = ((const float4*)&Vt[vrow])[0];
        float4 vr1 = ((const float4*)&Vt[vrow])[1];
        const ushort* bt = &biasT[((size_t)(qt * (qt + 1) / 2) * 256 + tid) * 16];
        s16x8 bn0 = *(const s16x8*)bt;
        s16x8 bn1 = *(const s16x8*)(bt + 8);

        for (int t = 0; t <= qt; t++) {
            int j0 = t * 64;
            __syncthreads();          // prior compute done; LDS free
            *(float4*)&Ks[skey][scol]     = kr0;
            *(float4*)&Ks[skey][scol + 8] = kr1;
            *(float4*)&Vs[skey][scol]     = vr0;
            *(float4*)&Vs[skey][scol + 8] = vr1;
            s16x8 b0 = bn0, b1 = bn1;
            __syncthreads();

            // ---- prefetch tile t+1 (registers only; hides under compute)
            if (t < qt) {
                int j1 = j0 + 64;
                kr0 = ((const float4*)&Kbf[krow + (size_t)j1 * E_])[0];
                kr1 = ((const float4*)&Kbf[krow + (size_t)j1 * E_])[1];
                vr0 = ((const float4*)&Vt[vrow + j1])[0];
                vr1 = ((const float4*)&Vt[vrow + j1])[1];
                const ushort* btn = bt + (size_t)(t + 1) * 4096;
                bn0 = *(const s16x8*)btn;
                bn1 = *(const s16x8*)(btn + 8);
            }

            // ---- S = Q K^T : rows=q(quad*4+r), cols=key(kt*16+l15)
            f32x4 s[4];
#pragma unroll
            for (int kt = 0; kt < 4; kt++) {
                s16x8 kb0 = *(const s16x8*)&Ks[kt * 16 + l15][quad * 8];
                s16x8 kb1 = *(const s16x8*)&Ks[kt * 16 + l15][quad * 8 + 32];
                f32x4 acc = (f32x4){0.f, 0.f, 0.f, 0.f};
                acc = __builtin_amdgcn_mfma_f32_16x16x32_bf16(qa0, kb0, acc, 0, 0, 0);
                acc = __builtin_amdgcn_mfma_f32_16x16x32_bf16(qa1, kb1, acc, 0, 0, 0);
                s[kt] = acc;
            }

            // ---- p = exp2(s*scale*l2e + biasT); causal mask -> 0; XOR-swizzled P
            bool diag = (t == qt);
#pragma unroll
            for (int r = 0; r < 4; r++) {
                int row = q0w + quad * 4 + r;
#pragma unroll
                for (int kt = 0; kt < 4; kt++) {
                    int j = j0 + kt * 16 + l15;
                    int idx = r * 4 + kt;
                    ushort ub = (ushort)((idx < 8) ? b0[idx] : b1[idx - 8]);
                    union { unsigned u; float f; } bc; bc.u = ((unsigned)ub) << 16;
                    float v = fmaf(s[kt][r], scale_l2e, bc.f);
                    float p = (diag && j > row) ? 0.f : fast_exp2(v);
                    lsum[r] += p;
                    int chunk = (kt * 2 + (l15 >> 3)) ^ quad;
                    Ps[wid][quad * 4 + r][chunk * 8 + (l15 & 7)] = f2bf(p);
                }
            }

            // ---- O += P V  (Ps wave-private: no barrier)
            int cb = (quad ^ (l15 >> 2)) * 8;
            s16x8 pa0 = *(const s16x8*)&Ps[wid][l15][cb];
            s16x8 pa1 = *(const s16x8*)&Ps[wid][l15][cb + 32];
#pragma unroll
            for (int dt = 0; dt < 4; dt++) {
                s16x8 vb0 = *(const s16x8*)&Vs[dt * 16 + l15][quad * 8];
                s16x8 vb1 = *(const s16x8*)&Vs[dt * 16 + l15][quad * 8 + 32];
                o[dt] = __builtin_amdgcn_mfma_f32_16x16x32_bf16(pa0, vb0, o[dt], 0, 0, 0);
                o[dt] = __builtin_amdgcn_mfma_f32_16x16x32_bf16(pa1, vb1, o[dt], 0, 0, 0);
            }
        }

        // ---- single final row-sum reduction
        float inv_l[4];
#pragma unroll
        for (int r = 0; r < 4; r++) {
            float l = lsum[r];
            l += __shfl_xor(l, 1);
            l += __shfl_xor(l, 2);
            l += __shfl_xor(l, 4);
            l += __shfl_xor(l, 8);
            inv_l[r] = 1.f / l;
        }

#pragma unroll
        for (int dt = 0; dt < 4; dt++) {
#pragma unroll
            for (int r = 0; r < 4; r++) {
                int row = q0w + quad * 4 + r;
                Ctx[((size_t)(b * S_ + row)) * E_ + h * 64 + dt * 16 + l15] =
                    f2bf(o[dt][r] * inv_l[r]);
            }
        }
    }
}

// ---------------------------------------------------------------------------
extern "C" void kernel_launch(void* const* d_in, const int* in_sizes, int n_in,
                              void* d_out, int out_size, void* d_ws, size_t ws_size,
                              hipStream_t stream) {
    const float* X     = (const float*)d_in[0];
    const float* abias = (const float*)d_in[1];
    const float* Wqkv  = (const float*)d_in[2];
    const float* bqkv  = (const float*)d_in[3];
    const float* Wproj = (const float*)d_in[4];
    const float* bproj = (const float*)d_in[5];

    const size_t plane = (size_t)B_ * S_ * E_;   // 4,194,304
    float* out  = (float*)d_out;
    float* kout = out + plane;                   // cache_key (fp32 output)
    float* vout = kout + plane;                  // cache_value (fp32 output)

    // workspace: 4 bf16 planes + weights = 42 MB (proven footprint).
    // ctxbf ALIASES xbf (X's bf16 copy is dead after the QKV GEMM).
    // biasT ALIASES wqkvt (Wqkv^T is dead after the QKV GEMM; biasT is
    // 528*4096 ushorts = 4.3 MB <= wqkvt's 6 MB, written after the GEMM).
    ushort* xbf    = (ushort*)d_ws;
    ushort* qbf    = xbf + plane;
    ushort* kbf    = qbf + plane;
    ushort* vt     = kbf + plane;
    ushort* ctxbf  = xbf;                        // alias (see above)
    ushort* wqkvt  = vt + plane;                 // [3E][E]
    ushort* wprojt = wqkvt + (size_t)3 * E_ * E_;// [E][E]
    ushort* biasT  = wqkvt;                      // alias (see above)

    const int M = B_ * S_;

    cvtx_kernel<<<dim3(plane / 1024), 256, 0, stream>>>(X, xbf);
    wtrans_kernel<<<dim3(3 * E_ / 64, E_ / 64), 256, 0, stream>>>(Wqkv, wqkvt, E_, 3 * E_);
    wtrans_kernel<<<dim3(E_ / 64, E_ / 64), 256, 0, stream>>>(Wproj, wprojt, E_, E_);

    gemm_mfma_bt<<<dim3(3 * E_ / 128, M / 128), 256, 0, stream>>>(
        xbf, wqkvt, bqkv, M, 3 * E_, E_,
        nullptr, qbf, kout, kbf, vout, 1);

    vtrans_kernel<<<dim3(B_ * H_ * (S_ / 64)), 256, 0, stream>>>(vout, vt);

    // bias pre-pack (writes over dead wqkvt region)
    prep_bias_kernel<<<dim3(528), 256, 0, stream>>>(abias, biasT);

    // flash attention: 512 paired blocks; XCD = pr%8 for biasT L2 locality
    attn_mfma_kernel<<<dim3(B_ * H_ * 16), 256, 0, stream>>>(
        qbf, kbf, vt, biasT, ctxbf);

    gemm_mfma_bt<<<dim3(E_ / 128, M / 128), 256, 0, stream>>>(
        ctxbf, wprojt, bproj, M, E_, E_,
        out, nullptr, nullptr, nullptr, nullptr, 0);
}

// Round 6
// 235.043 us; speedup vs baseline: 1.3966x; 1.0092x over previous
//
#include <hip/hip_runtime.h>

#define B_ 2
#define S_ 2048
#define E_ 1024
#define H_ 16
#define D_ 64

typedef short  s16x8 __attribute__((ext_vector_type(8)));
typedef float  f32x4 __attribute__((ext_vector_type(4)));
typedef unsigned short u16x4 __attribute__((ext_vector_type(4)));

__device__ __forceinline__ ushort f2bf(float f) {
    union { float f; unsigned u; } x; x.f = f;
    unsigned u = x.u + 0x7fffu + ((x.u >> 16) & 1u);   // RNE
    return (ushort)(u >> 16);
}

__device__ __forceinline__ float fast_exp2(float x) {
    float r; asm("v_exp_f32 %0, %1" : "=v"(r) : "v"(x)); return r;
}

// ---------------------------------------------------------------------------
// X fp32 -> bf16 (flat, 4 elems/thread)
// ---------------------------------------------------------------------------
__global__ __launch_bounds__(256) void cvtx_kernel(
    const float* __restrict__ X, ushort* __restrict__ Xbf)
{
    int i = (blockIdx.x * 256 + threadIdx.x) * 4;
    float4 v = *(const float4*)&X[i];
    u16x4 o;
    o.x = f2bf(v.x); o.y = f2bf(v.y); o.z = f2bf(v.z); o.w = f2bf(v.w);
    *(u16x4*)&Xbf[i] = o;
}

// ---------------------------------------------------------------------------
// W fp32 [Kdim][Ndim] -> Wt bf16 [Ndim][Kdim]  (64x64 LDS tiles)
// ---------------------------------------------------------------------------
__global__ __launch_bounds__(256) void wtrans_kernel(
    const float* __restrict__ W, ushort* __restrict__ Wt, int Kdim, int Ndim)
{
    __shared__ float tile[64][65];
    int n0 = blockIdx.x * 64, k0 = blockIdx.y * 64;
    int tid = threadIdx.x;
    int c = tid & 63;
#pragma unroll
    for (int r = tid >> 6; r < 64; r += 4)
        tile[r][c] = W[(size_t)(k0 + r) * Ndim + n0 + c];
    __syncthreads();
#pragma unroll
    for (int r = tid >> 6; r < 64; r += 4)
        Wt[(size_t)(n0 + r) * Kdim + k0 + c] = f2bf(tile[c][r]);
}

// ---------------------------------------------------------------------------
// bias fp32 [S][S] -> biasT bf16, causal-packed tile layout, pre-scaled by
// log2(e).  Tile (qi,ki), ki<=qi, L = qi(qi+1)/2 + ki.
// biasT[L*4096 + tid*16 + (r*4+kt)] = bf16(bias[qi*64 + (tid>>6)*16 +
//   ((tid>>4)&3)*4 + r][ki*64 + kt*16 + (tid&15)] * LOG2E)
// Each attn thread's 16 bias values for a tile are CONTIGUOUS (32B).
// ---------------------------------------------------------------------------
__global__ __launch_bounds__(256) void prep_bias_kernel(
    const float* __restrict__ bias, ushort* __restrict__ biasT)
{
    int L = blockIdx.x;
    int qi = (int)((sqrtf(8.0f * (float)L + 1.0f) - 1.0f) * 0.5f);
    while ((qi + 1) * (qi + 2) / 2 <= L) qi++;
    while (qi * (qi + 1) / 2 > L) qi--;
    int ki = L - qi * (qi + 1) / 2;
    int tid = threadIdx.x;
    int w = tid >> 6, quad = (tid >> 4) & 3, l15 = tid & 15;
    const float LOG2E = 1.4426950408889634f;
    s16x8 h0 = (s16x8){0,0,0,0,0,0,0,0}, h1 = (s16x8){0,0,0,0,0,0,0,0};
#pragma unroll
    for (int r = 0; r < 4; r++)
#pragma unroll
        for (int kt = 0; kt < 4; kt++) {
            float v = bias[(size_t)(qi * 64 + w * 16 + quad * 4 + r) * S_
                           + ki * 64 + kt * 16 + l15] * LOG2E;
            ushort u = f2bf(v);
            int idx = r * 4 + kt;
            if (idx < 8) h0[idx] = (short)u; else h1[idx - 8] = (short)u;
        }
    ushort* dst = &biasT[((size_t)L * 256 + tid) * 16];
    *(s16x8*)dst = h0;
    *(s16x8*)(dst + 8) = h1;
}

// ---------------------------------------------------------------------------
// bf16 MFMA GEMM (m97 structure): C[m][n] = sum_k A[m][k]*Bt[n][k] + bias[n]
// 128x128 tile, BK=32, global_load_lds w=16, ds_read_b128 frags.
// mode 0: fp32 C0. mode 1 (N=3E): seg0->Qbf, seg1->Kf32+Kbf, seg2->Vf32.
// ---------------------------------------------------------------------------
__global__ __launch_bounds__(256) void gemm_mfma_bt(
    const ushort* __restrict__ A,    // [M][K] bf16
    const ushort* __restrict__ Bt,   // [N][K] bf16
    const float* __restrict__ bias,  // [N]
    int M, int N, int K,
    float* __restrict__ C0,
    ushort* __restrict__ Qbf, float* __restrict__ Kf32, ushort* __restrict__ Kbf,
    float* __restrict__ Vf32, int mode)
{
    __shared__ ushort As[128 * 32];
    __shared__ ushort Bs[128 * 32];
    int tid = threadIdx.x;
    int wid = tid >> 6, lane = tid & 63;
    int l15 = lane & 15, quad = lane >> 4;
    int wm = wid >> 1, wn = wid & 1;
    int row0 = blockIdx.y * 128, col0 = blockIdx.x * 128;

    int sr = wid * 16 + (lane >> 2);
    int sk = (lane & 3) * 8;

    f32x4 acc[4][4];
#pragma unroll
    for (int mt = 0; mt < 4; mt++)
#pragma unroll
        for (int nt = 0; nt < 4; nt++) acc[mt][nt] = (f32x4){0.f, 0.f, 0.f, 0.f};

    for (int k0 = 0; k0 < K; k0 += 32) {
        __syncthreads();
#pragma unroll
        for (int c = 0; c < 2; c++) {
            int r = c * 64 + sr;
            __builtin_amdgcn_global_load_lds(
                (const __attribute__((address_space(1))) unsigned int*)
                    &A[(size_t)(row0 + r) * K + k0 + sk],
                (__attribute__((address_space(3))) unsigned int*)&As[r * 32 + sk],
                16, 0, 0);
            __builtin_amdgcn_global_load_lds(
                (const __attribute__((address_space(1))) unsigned int*)
                    &Bt[(size_t)(col0 + r) * K + k0 + sk],
                (__attribute__((address_space(3))) unsigned int*)&Bs[r * 32 + sk],
                16, 0, 0);
        }
        __syncthreads();

        s16x8 af[4], bf[4];
#pragma unroll
        for (int mt = 0; mt < 4; mt++)
            af[mt] = *(const s16x8*)&As[(wm * 64 + mt * 16 + l15) * 32 + quad * 8];
#pragma unroll
        for (int nt = 0; nt < 4; nt++)
            bf[nt] = *(const s16x8*)&Bs[(wn * 64 + nt * 16 + l15) * 32 + quad * 8];
#pragma unroll
        for (int mt = 0; mt < 4; mt++)
#pragma unroll
            for (int nt = 0; nt < 4; nt++)
                acc[mt][nt] = __builtin_amdgcn_mfma_f32_16x16x32_bf16(
                    af[mt], bf[nt], acc[mt][nt], 0, 0, 0);
    }

#pragma unroll
    for (int nt = 0; nt < 4; nt++) {
        int n = col0 + wn * 64 + nt * 16 + l15;
        float bv = bias[n];
        if (mode == 1) {
            int seg = n >> 10;
            int nn = n & (E_ - 1);
#pragma unroll
            for (int mt = 0; mt < 4; mt++)
#pragma unroll
                for (int r = 0; r < 4; r++) {
                    int row = row0 + wm * 64 + mt * 16 + quad * 4 + r;
                    float v = acc[mt][nt][r] + bv;
                    size_t idx = (size_t)row * E_ + nn;
                    if (seg == 0)      Qbf[idx] = f2bf(v);
                    else if (seg == 1) { Kf32[idx] = v; Kbf[idx] = f2bf(v); }
                    else               Vf32[idx] = v;
                }
        } else {
#pragma unroll
            for (int mt = 0; mt < 4; mt++)
#pragma unroll
                for (int r = 0; r < 4; r++) {
                    int row = row0 + wm * 64 + mt * 16 + quad * 4 + r;
                    C0[(size_t)row * N + n] = acc[mt][nt][r] + bv;
                }
        }
    }
}

// ---------------------------------------------------------------------------
// V transpose: fp32 V [b*S+s][h*64+d] -> bf16 Vt [(b*H+h)*64+d][s]
// ---------------------------------------------------------------------------
__global__ __launch_bounds__(256) void vtrans_kernel(
    const float* __restrict__ V, ushort* __restrict__ Vt)
{
    __shared__ float tile[64][65];
    int blk = blockIdx.x;
    int s0 = (blk & 31) * 64;
    int bh = blk >> 5;
    int b = bh >> 4, h = bh & 15;
    int tid = threadIdx.x;
    int d = tid & 63;
#pragma unroll
    for (int i = tid >> 6; i < 64; i += 4)
        tile[i][d] = V[((size_t)(b * S_ + s0 + i)) * E_ + h * 64 + d];
    __syncthreads();
    int lane = tid & 63, w = tid >> 6;
#pragma unroll
    for (int dd = w; dd < 64; dd += 4)
        Vt[((size_t)(bh * 64 + dd)) * S_ + s0 + lane] = f2bf(tile[lane][dd]);
}

// ---------------------------------------------------------------------------
// MFMA flash attention, fixed-reference softmax — round 11.
// R5 post-mortem: biasT worked (60->54us) but (a) pr%8 XCD mapping destroyed
// K/V L2 locality (FETCH 50->98MB) and (b) bank conflicts stayed at 4.87M,
// of which 4.3M are from the K/V 72-ushort pad: frag ds_read_b128 bank-start
// 4*(l15+quad)%32 aliases lanes 0-7 vs 8-15 per quad (~15% of CU cycles).
// Fixes, keeping the proven R0 schedule byte-for-byte:
//  1. mapping restored to bh = blk&31 (XCD = bh%8): K+Vt working set 2MB/XCD
//     fits L2. biasT shares 4-way per XCD (concurrent same-pr blocks).
//  2. Ks/Vs = [64][64] linear with 16B-chunk XOR swizzle: chunk ^= (row&7),
//     applied on BOTH staging writes and frag reads. Per-8-lane-phase bank
//     arithmetic: all staging writes and all frag reads conflict-free.
// Ps (wave-private, its own XOR swizzle) unchanged; biasT consumption
// (exp2-direct, pre-scaled) unchanged.
// ---------------------------------------------------------------------------
__global__ __launch_bounds__(256) void attn_mfma_kernel(
    const ushort* __restrict__ Qbf,   // [B*S, E] bf16
    const ushort* __restrict__ Kbf,   // [B*S, E] bf16
    const ushort* __restrict__ Vt,    // [(b*H+h)*64+d][S] bf16
    const ushort* __restrict__ biasT, // causal-packed bf16 tiles (prep_bias)
    ushort* __restrict__ Ctx)         // [B*S, E] bf16
{
    __shared__ ushort Ks[64][64];
    __shared__ ushort Vs[64][64];
    __shared__ ushort Ps[4][16][72];

    int blk = blockIdx.x;
    int bh = blk & 31;               // XCD = bh%8 -> K/V L2 locality (R0)
    int pr = blk >> 5;               // 0..15
    int b = bh >> 4, h = bh & 15;
    int tid = threadIdx.x;
    int wid = tid >> 6, lane = tid & 63;
    int l15 = lane & 15, quad = lane >> 4;

    int skey = tid >> 2;
    int scol = (tid & 3) * 16;       // ushort col of this thread's 16B pair
    // swizzled staging chunk offsets (ushort units): chunk ^= (skey&7)
    int sc0 = ((((tid & 3) * 2) ^ (skey & 7)) * 8);
    int sc1 = sc0 ^ 8;
    const float scale_l2e = 0.18033688011112042f;   // 0.125 * log2(e)

    const size_t krow = (size_t)(b * S_ + skey) * E_ + h * 64 + scol; // + j0*E_
    const size_t vrow = (size_t)(bh * 64 + skey) * S_ + scol;        // + j0

    // swizzled frag-read chunk base: logical chunk quad, row&7 = l15&7
    int rc0 = (quad ^ (l15 & 7)) * 8;

    for (int half = 0; half < 2; half++) {
        int qt = half ? pr : (31 - pr);
        int q0w = qt * 64 + wid * 16;

        // Q fragments (A-layout)
        const size_t qbase = ((size_t)(b * S_ + q0w + l15)) * E_ + h * 64 + quad * 8;
        s16x8 qa0 = *(const s16x8*)&Qbf[qbase];
        s16x8 qa1 = *(const s16x8*)&Qbf[qbase + 32];

        f32x4 o[4];
#pragma unroll
        for (int dt = 0; dt < 4; dt++) o[dt] = (f32x4){0.f, 0.f, 0.f, 0.f};
        float lsum[4];
#pragma unroll
        for (int r = 0; r < 4; r++) lsum[r] = 0.f;

        // ---- preload tile 0 into registers
        float4 kr0 = ((const float4*)&Kbf[krow])[0];
        float4 kr1 = ((const float4*)&Kbf[krow])[1];
        float4 vr0 = ((const float4*)&Vt[vrow])[0];
        float4 vr1 = ((const float4*)&Vt[vrow])[1];
        const ushort* bt = &biasT[((size_t)(qt * (qt + 1) / 2) * 256 + tid) * 16];
        s16x8 bn0 = *(const s16x8*)bt;
        s16x8 bn1 = *(const s16x8*)(bt + 8);

        for (int t = 0; t <= qt; t++) {
            int j0 = t * 64;
            __syncthreads();          // prior compute done; LDS free
            *(float4*)&Ks[skey][sc0] = kr0;
            *(float4*)&Ks[skey][sc1] = kr1;
            *(float4*)&Vs[skey][sc0] = vr0;
            *(float4*)&Vs[skey][sc1] = vr1;
            s16x8 b0 = bn0, b1 = bn1;
            __syncthreads();

            // ---- prefetch tile t+1 (registers only; hides under compute)
            if (t < qt) {
                int j1 = j0 + 64;
                kr0 = ((const float4*)&Kbf[krow + (size_t)j1 * E_])[0];
                kr1 = ((const float4*)&Kbf[krow + (size_t)j1 * E_])[1];
                vr0 = ((const float4*)&Vt[vrow + j1])[0];
                vr1 = ((const float4*)&Vt[vrow + j1])[1];
                const ushort* btn = bt + (size_t)(t + 1) * 4096;
                bn0 = *(const s16x8*)btn;
                bn1 = *(const s16x8*)(btn + 8);
            }

            // ---- S = Q K^T : rows=q(quad*4+r), cols=key(kt*16+l15)
            f32x4 s[4];
#pragma unroll
            for (int kt = 0; kt < 4; kt++) {
                s16x8 kb0 = *(const s16x8*)&Ks[kt * 16 + l15][rc0];
                s16x8 kb1 = *(const s16x8*)&Ks[kt * 16 + l15][rc0 ^ 32];
                f32x4 acc = (f32x4){0.f, 0.f, 0.f, 0.f};
                acc = __builtin_amdgcn_mfma_f32_16x16x32_bf16(qa0, kb0, acc, 0, 0, 0);
                acc = __builtin_amdgcn_mfma_f32_16x16x32_bf16(qa1, kb1, acc, 0, 0, 0);
                s[kt] = acc;
            }

            // ---- p = exp2(s*scale*l2e + biasT); causal mask -> 0; XOR-swizzled P
            bool diag = (t == qt);
#pragma unroll
            for (int r = 0; r < 4; r++) {
                int row = q0w + quad * 4 + r;
#pragma unroll
                for (int kt = 0; kt < 4; kt++) {
                    int j = j0 + kt * 16 + l15;
                    int idx = r * 4 + kt;
                    ushort ub = (ushort)((idx < 8) ? b0[idx] : b1[idx - 8]);
                    union { unsigned u; float f; } bc; bc.u = ((unsigned)ub) << 16;
                    float v = fmaf(s[kt][r], scale_l2e, bc.f);
                    float p = (diag && j > row) ? 0.f : fast_exp2(v);
                    lsum[r] += p;
                    int chunk = (kt * 2 + (l15 >> 3)) ^ quad;
                    Ps[wid][quad * 4 + r][chunk * 8 + (l15 & 7)] = f2bf(p);
                }
            }

            // ---- O += P V  (Ps wave-private: no barrier)
            int cb = (quad ^ (l15 >> 2)) * 8;
            s16x8 pa0 = *(const s16x8*)&Ps[wid][l15][cb];
            s16x8 pa1 = *(const s16x8*)&Ps[wid][l15][cb + 32];
#pragma unroll
            for (int dt = 0; dt < 4; dt++) {
                s16x8 vb0 = *(const s16x8*)&Vs[dt * 16 + l15][rc0];
                s16x8 vb1 = *(const s16x8*)&Vs[dt * 16 + l15][rc0 ^ 32];
                o[dt] = __builtin_amdgcn_mfma_f32_16x16x32_bf16(pa0, vb0, o[dt], 0, 0, 0);
                o[dt] = __builtin_amdgcn_mfma_f32_16x16x32_bf16(pa1, vb1, o[dt], 0, 0, 0);
            }
        }

        // ---- single final row-sum reduction
        float inv_l[4];
#pragma unroll
        for (int r = 0; r < 4; r++) {
            float l = lsum[r];
            l += __shfl_xor(l, 1);
            l += __shfl_xor(l, 2);
            l += __shfl_xor(l, 4);
            l += __shfl_xor(l, 8);
            inv_l[r] = 1.f / l;
        }

#pragma unroll
        for (int dt = 0; dt < 4; dt++) {
#pragma unroll
            for (int r = 0; r < 4; r++) {
                int row = q0w + quad * 4 + r;
                Ctx[((size_t)(b * S_ + row)) * E_ + h * 64 + dt * 16 + l15] =
                    f2bf(o[dt][r] * inv_l[r]);
            }
        }
    }
}

// ---------------------------------------------------------------------------
extern "C" void kernel_launch(void* const* d_in, const int* in_sizes, int n_in,
                              void* d_out, int out_size, void* d_ws, size_t ws_size,
                              hipStream_t stream) {
    const float* X     = (const float*)d_in[0];
    const float* abias = (const float*)d_in[1];
    const float* Wqkv  = (const float*)d_in[2];
    const float* bqkv  = (const float*)d_in[3];
    const float* Wproj = (const float*)d_in[4];
    const float* bproj = (const float*)d_in[5];

    const size_t plane = (size_t)B_ * S_ * E_;   // 4,194,304
    float* out  = (float*)d_out;
    float* kout = out + plane;                   // cache_key (fp32 output)
    float* vout = kout + plane;                  // cache_value (fp32 output)

    // workspace: 4 bf16 planes + weights = 42 MB (proven footprint).
    // ctxbf ALIASES xbf (X's bf16 copy is dead after the QKV GEMM).
    // biasT ALIASES wqkvt (Wqkv^T dead after the QKV GEMM; 4.3MB <= 6MB).
    ushort* xbf    = (ushort*)d_ws;
    ushort* qbf    = xbf + plane;
    ushort* kbf    = qbf + plane;
    ushort* vt     = kbf + plane;
    ushort* ctxbf  = xbf;                        // alias (see above)
    ushort* wqkvt  = vt + plane;                 // [3E][E]
    ushort* wprojt = wqkvt + (size_t)3 * E_ * E_;// [E][E]
    ushort* biasT  = wqkvt;                      // alias (see above)

    const int M = B_ * S_;

    cvtx_kernel<<<dim3(plane / 1024), 256, 0, stream>>>(X, xbf);
    wtrans_kernel<<<dim3(3 * E_ / 64, E_ / 64), 256, 0, stream>>>(Wqkv, wqkvt, E_, 3 * E_);
    wtrans_kernel<<<dim3(E_ / 64, E_ / 64), 256, 0, stream>>>(Wproj, wprojt, E_, E_);

    gemm_mfma_bt<<<dim3(3 * E_ / 128, M / 128), 256, 0, stream>>>(
        xbf, wqkvt, bqkv, M, 3 * E_, E_,
        nullptr, qbf, kout, kbf, vout, 1);

    vtrans_kernel<<<dim3(B_ * H_ * (S_ / 64)), 256, 0, stream>>>(vout, vt);

    // bias pre-pack (writes over dead wqkvt region)
    prep_bias_kernel<<<dim3(528), 256, 0, stream>>>(abias, biasT);

    // flash attention: 512 paired blocks; XCD = bh%8 for K/V L2 locality
    attn_mfma_kernel<<<dim3(B_ * H_ * 16), 256, 0, stream>>>(
        qbf, kbf, vt, biasT, ctxbf);

    gemm_mfma_bt<<<dim3(E_ / 128, M / 128), 256, 0, stream>>>(
        ctxbf, wprojt, bproj, M, E_, E_,
        out, nullptr, nullptr, nullptr, nullptr, 0);
}